// Round 7
// baseline (410.151 us; speedup 1.0000x reference)
//
#include <hip/hip_runtime.h>
#include <math.h>

#define N 512
#define H 12
#define CC 16      // C
#define CZ 128
#define CS 384
#define PQ 4
#define PV 8
#define CATR 2017

// ---------------------------------------------------------------------------
// Kernel 1: all projections. out[o,n] = sum_c W_sel[o][c] * s[c,n], o in [0,1152)
// q rows (o<192) PRE-SCALED by 0.25 (consumed only by the qk/4 term).
// ---------------------------------------------------------------------------
__global__ __launch_bounds__(256) void k_proj(
    const float* __restrict__ s,
    const float* __restrict__ Wq, const float* __restrict__ Wk, const float* __restrict__ Wv,
    const float* __restrict__ Wqp, const float* __restrict__ Wkp, const float* __restrict__ Wvp,
    float* __restrict__ proj)
{
    __shared__ float Wt[16][33];
    __shared__ float St[32][128];
    int t = threadIdx.x;
    int o0 = blockIdx.x * 16;
    int n0 = blockIdx.y * 128;
    const float* Wsrc; int orow;
    if (o0 < 192)      { Wsrc = Wq;  orow = o0; }
    else if (o0 < 384) { Wsrc = Wk;  orow = o0-192; }
    else if (o0 < 576) { Wsrc = Wv;  orow = o0-384; }
    else if (o0 < 720) { Wsrc = Wqp; orow = o0-576; }
    else if (o0 < 864) { Wsrc = Wkp; orow = o0-720; }
    else               { Wsrc = Wvp; orow = o0-864; }

    int og = t >> 6, nl = t & 63;
    float acc[4][2] = {};
    for (int c0 = 0; c0 < CS; c0 += 32) {
        __syncthreads();
        for (int k = 0; k < 2; k++) {
            int idx = t + k*256;
            int oo = idx >> 5, ccol = idx & 31;
            Wt[oo][ccol] = Wsrc[(orow+oo)*CS + c0 + ccol];
        }
        for (int k = 0; k < 4; k++) {
            int idx = t + k*256;
            int ccr = idx >> 5, nn4 = idx & 31;
            float4 v = *(const float4*)&s[(c0+ccr)*N + n0 + nn4*4];
            *(float4*)&St[ccr][nn4*4] = v;
        }
        __syncthreads();
        for (int kk = 0; kk < 32; kk++) {
            float sv0 = St[kk][nl], sv1 = St[kk][nl+64];
            #pragma unroll
            for (int r = 0; r < 4; r++) {
                float w = Wt[og*4+r][kk];
                acc[r][0] += w * sv0;
                acc[r][1] += w * sv1;
            }
        }
    }
    float scale = (o0 < 192) ? 0.25f : 1.0f;
    for (int r = 0; r < 4; r++) {
        int o = o0 + og*4 + r;
        proj[o*N + n0 + nl]      = scale * acc[r][0];
        proj[o*N + n0 + 64 + nl] = scale * acc[r][1];
    }
}

// ---------------------------------------------------------------------------
// Kernel 2: apply frames.
// ---------------------------------------------------------------------------
__global__ void k_frames(const float* __restrict__ proj,
                         const float* __restrict__ t_r, const float* __restrict__ t_t,
                         float* __restrict__ qg, float* __restrict__ kg, float* __restrict__ vg)
{
    int gid = blockIdx.x * blockDim.x + threadIdx.x;
    int n = gid & (N-1);
    int hp = gid >> 9;
    if (hp >= 192) return;
    const float* src; float* dst; int rowb, stride;
    if (hp < 48)      { src = proj + 576*N; dst = qg; rowb = hp;    stride = 48; }
    else if (hp < 96) { src = proj + 720*N; dst = kg; rowb = hp-48; stride = 48; }
    else              { src = proj + 864*N; dst = vg; rowb = hp-96; stride = 96; }
    float x0 = src[(rowb + 0*stride)*N + n];
    float x1 = src[(rowb + 1*stride)*N + n];
    float x2 = src[(rowb + 2*stride)*N + n];
    #pragma unroll
    for (int d = 0; d < 3; d++) {
        float r0 = t_r[(n*3+d)*3+0], r1 = t_r[(n*3+d)*3+1], r2 = t_r[(n*3+d)*3+2];
        dst[(rowb + d*stride)*N + n] = r0*x0 + r1*x1 + r2*x2 + t_t[n*3+d];
    }
}

// ---------------------------------------------------------------------------
// Kernel 3a: qk + geometric logit partial as a tiled outer-product GEMM.
// Writes raw partial into `a`.  (R6-proven.)
// ---------------------------------------------------------------------------
__global__ __launch_bounds__(256) void k_qkgeom(
    const float* __restrict__ proj, const float* __restrict__ qg,
    const float* __restrict__ kg, const float* __restrict__ gamma,
    float* __restrict__ a)
{
    __shared__ float Qe[30][32];
    __shared__ float Ke[30][128];
    const int h  = blockIdx.x;
    const int i0 = blockIdx.y * 32;
    const int j0 = blockIdx.z * 128;
    const int t  = threadIdx.x;
    const float w_c2 = 0.11785113019775793f;   // sqrt(1/18)/2
    float g = gamma[h];
    float sp = (g > 20.f) ? g : log1pf(expf(g));
    float ch = sp * w_c2;

    for (int idx = t; idx < 28*32; idx += 256) {
        int row = idx >> 5, col = idx & 31;
        float v;
        if (row < 16) v = proj[(size_t)(row*12 + h)*N + i0 + col];
        else { int dp = row-16, d = dp>>2, p = dp&3;
               v = 2.f*ch * qg[(size_t)(d*48 + h*4 + p)*N + i0 + col]; }
        Qe[row][col] = v;
    }
    for (int idx = t; idx < 28*128; idx += 256) {
        int row = idx >> 7, col = idx & 127;
        float v;
        if (row < 16) v = proj[(size_t)((192 + row*12 + h))*N + j0 + col];
        else { int dp = row-16, d = dp>>2, p = dp&3;
               v = kg[(size_t)(d*48 + h*4 + p)*N + j0 + col]; }
        Ke[row][col] = v;
    }
    if (t < 32) {
        float q2 = 0.f;
        #pragma unroll
        for (int dp = 0; dp < 12; ++dp) {
            int d = dp>>2, p = dp&3;
            float v = qg[(size_t)(d*48 + h*4 + p)*N + i0 + t];
            q2 = fmaf(v, v, q2);
        }
        Qe[28][t] = 1.f;
        Qe[29][t] = -ch * q2;
    } else if (t < 160) {
        int col = t - 32;
        float k2 = 0.f;
        #pragma unroll
        for (int dp = 0; dp < 12; ++dp) {
            int d = dp>>2, p = dp&3;
            float v = kg[(size_t)(d*48 + h*4 + p)*N + j0 + col];
            k2 = fmaf(v, v, k2);
        }
        Ke[28][col] = -ch * k2;
        Ke[29][col] = 1.f;
    }
    __syncthreads();

    const int tj = t & 31, ti = t >> 5;     // thread: 4 i rows x 4 j cols
    float acc[4][4] = {};
    #pragma unroll
    for (int c = 0; c < 30; ++c) {
        float4 k4 = *(const float4*)&Ke[c][tj*4];
        float4 q4 = *(const float4*)&Qe[c][ti*4];
        float qr[4] = {q4.x, q4.y, q4.z, q4.w};
        #pragma unroll
        for (int r = 0; r < 4; ++r) {
            acc[r][0] = fmaf(qr[r], k4.x, acc[r][0]);
            acc[r][1] = fmaf(qr[r], k4.y, acc[r][1]);
            acc[r][2] = fmaf(qr[r], k4.z, acc[r][2]);
            acc[r][3] = fmaf(qr[r], k4.w, acc[r][3]);
        }
    }
    #pragma unroll
    for (int r = 0; r < 4; ++r) {
        float4 v; v.x = acc[r][0]; v.y = acc[r][1]; v.z = acc[r][2]; v.w = acc[r][3];
        *(float4*)&a[((size_t)h*N + i0 + ti*4 + r)*N + j0 + tj*4] = v;
    }
}

// ---------------------------------------------------------------------------
// Kernel 3b: z-bias accumulation, RMW into `a`.  Massively parallel, no
// barrier in the stream path (R6's k_logits2 was grid-capped at 16 waves/CU
// with a barrier-locked tile loop -> 1.1 TB/s).  Grid (512 i, 8 j-slices of
// 64) = 4096 blocks; 256 thr = 64 j x 4 c-groups of 32.  16 loads in flight.
// ---------------------------------------------------------------------------
__global__ __launch_bounds__(256) void k_zbias(
    const float* __restrict__ z, const float* __restrict__ Wb,
    float* __restrict__ a)
{
    __shared__ float red[3*832];          // 3 slabs x 64j x 13(pad)
    const int i  = blockIdx.x;
    const int j0 = blockIdx.y * 64;
    const int t  = threadIdx.x;
    const int jl = t & 63, cg = t >> 6;
    const size_t NN = (size_t)N * N;

    const float* zp = z + (size_t)(cg*32)*NN + (size_t)i*N + j0 + jl;
    float acc[12] = {};
    for (int cc = 0; cc < 32; cc += 16) {
        float zb[16];
        #pragma unroll
        for (int u = 0; u < 16; ++u) zb[u] = zp[(size_t)(cc+u)*NN];
        #pragma unroll
        for (int h = 0; h < 12; ++h)
            #pragma unroll
            for (int u = 0; u < 16; ++u)
                acc[h] = fmaf(Wb[h*CZ + cg*32 + cc + u], zb[u], acc[h]);  // uniform s_load
    }
    if (cg > 0) {
        float* rb = &red[(cg-1)*832 + jl*13];
        #pragma unroll
        for (int h = 0; h < 12; ++h) rb[h] = acc[h];
    }
    __syncthreads();
    if (cg == 0) {
        #pragma unroll
        for (int sl = 0; sl < 3; ++sl) {
            const float* rb = &red[sl*832 + jl*13];
            #pragma unroll
            for (int h = 0; h < 12; ++h) acc[h] += rb[h];
        }
        #pragma unroll
        for (int h = 0; h < 12; ++h) {
            size_t idx = ((size_t)h*N + i)*N + j0 + jl;
            a[idx] = a[idx] + acc[h];     // RMW: single writer per element
        }
    }
}

// ---------------------------------------------------------------------------
// Kernel 3c: softmax over j, in place on `a` (scales by w_l).  Block per i,
// 512 threads (lane t = j); two-level reduce (shfl intra-wave, LDS cross-wave).
// ---------------------------------------------------------------------------
__global__ __launch_bounds__(512) void k_softmax(float* __restrict__ a)
{
    __shared__ float pm[12][8];
    __shared__ float ps[12][8];
    const int i = blockIdx.x;
    const int t = threadIdx.x;
    const int w = t >> 6;
    const int l = t & 63;
    const float w_l = 0.57735026918962584f;   // sqrt(1/3)

    float lv[12], mw[12];
    #pragma unroll
    for (int h = 0; h < 12; ++h)
        lv[h] = w_l * a[((size_t)h*N + i)*N + t];

    #pragma unroll
    for (int h = 0; h < 12; ++h) {
        float m = lv[h];
        for (int s = 32; s; s >>= 1) m = fmaxf(m, __shfl_xor(m, s));
        float e = __expf(lv[h] - m);
        float sm = e;
        for (int s = 32; s; s >>= 1) sm += __shfl_xor(sm, s);
        lv[h] = e; mw[h] = m;
        if (l == 0) { pm[h][w] = m; ps[h][w] = sm; }
    }
    __syncthreads();
    #pragma unroll
    for (int h = 0; h < 12; ++h) {
        float mg = pm[h][0];
        #pragma unroll
        for (int u = 1; u < 8; ++u) mg = fmaxf(mg, pm[h][u]);
        float sg = 0.f;
        #pragma unroll
        for (int u = 0; u < 8; ++u) sg += ps[h][u] * __expf(pm[h][u] - mg);
        float f = __expf(mw[h] - mg) / sg;       // uniform per (wave,h)
        a[((size_t)h*N + i)*N + t] = lv[h] * f;
    }
}

// ---------------------------------------------------------------------------
// Kernel 4: o1 = sum_j a[h,i,j]*z[c,i,j].  Grid (512 i, 2 c-halves), all j
// in-block.  Output to o1T[i][c*12+h] (transposed -> coalesced writes).
// ---------------------------------------------------------------------------
__global__ __launch_bounds__(256, 8) void k_o1(
    const float* __restrict__ a, const float* __restrict__ z,
    float* __restrict__ o1T)
{
    __shared__ float zls[64*36];     // 9.2 KB: z half-tile 64c x 32j; reduce slabs after
    __shared__ float als[12][36];    // 1.7 KB: a tile 12 x 32j
    const int i  = blockIdx.x;
    const int c0 = blockIdx.y * 64;
    const int t  = threadIdx.x;
    const int cg = t & 31, hg = (t >> 5) & 1, jq = t >> 6;

    float acc[2][6] = {};
    for (int jc = 0; jc < 16; ++jc) {
        __syncthreads();
        #pragma unroll
        for (int k = 0; k < 2; ++k) {        // stage z: 64c x 32j
            int idx = t + k*256;
            int c = idx >> 3, j4 = idx & 7;
            *(float4*)&zls[c*36 + j4*4] =
                *(const float4*)&z[((size_t)(c0+c)*N + i)*N + jc*32 + j4*4];
        }
        if (t < 96) {                        // stage a: 12h x 32j
            int h = t >> 3, j4 = t & 7;
            *(float4*)&als[h][j4*4] =
                *(const float4*)&a[((size_t)h*N + i)*N + jc*32 + j4*4];
        }
        __syncthreads();
        #pragma unroll
        for (int s = 0; s < 2; ++s) {
            int jo = jq*8 + s*4;
            float4 a4[6];
            #pragma unroll
            for (int hh = 0; hh < 6; ++hh)
                a4[hh] = *(const float4*)&als[hg*6+hh][jo];   // broadcast
            #pragma unroll
            for (int r = 0; r < 2; ++r) {
                float4 z4 = *(const float4*)&zls[(cg + 32*r)*36 + jo];
                #pragma unroll
                for (int hh = 0; hh < 6; ++hh)
                    acc[r][hh] += z4.x*a4[hh].x + z4.y*a4[hh].y
                                + z4.z*a4[hh].z + z4.w*a4[hh].w;
            }
        }
    }
    // cross-wave (jq) reduce via slabs in zls; stride 13 = conflict-light
    const int sl = t & 63;
    __syncthreads();
    if (jq >= 2) {
        float* rb = &zls[(jq-2)*832 + sl*13];
        #pragma unroll
        for (int r = 0; r < 2; ++r)
            #pragma unroll
            for (int hh = 0; hh < 6; ++hh) rb[r*6+hh] = acc[r][hh];
    }
    __syncthreads();
    if (jq < 2) {
        const float* rb = &zls[jq*832 + sl*13];
        #pragma unroll
        for (int r = 0; r < 2; ++r)
            #pragma unroll
            for (int hh = 0; hh < 6; ++hh) acc[r][hh] += rb[r*6+hh];
    }
    __syncthreads();                          // slab0 reads done before jq1 overwrites
    if (jq == 1) {
        float* rb = &zls[sl*13];
        #pragma unroll
        for (int r = 0; r < 2; ++r)
            #pragma unroll
            for (int hh = 0; hh < 6; ++hh) rb[r*6+hh] = acc[r][hh];
    }
    __syncthreads();
    if (jq == 0) {
        const float* rb = &zls[sl*13];
        #pragma unroll
        for (int r = 0; r < 2; ++r)
            #pragma unroll
            for (int hh = 0; hh < 3; ++hh) {
                int c = c0 + cg + 32*r, h = hg*6 + hh*2;
                float2 v2;
                v2.x = acc[r][hh*2]   + rb[r*6+hh*2];
                v2.y = acc[r][hh*2+1] + rb[r*6+hh*2+1];
                *(float2*)&o1T[(size_t)i*1536 + c*12 + h] = v2;
            }
    }
}

// ---------------------------------------------------------------------------
// Kernel 5: o2 + o3g. grid (12 h, 64 i-tiles of 8). 4-way j split.
// o2 -> catB rows [0,192); o3g unchanged.
// ---------------------------------------------------------------------------
__global__ __launch_bounds__(256) void k_o2o3g(
    const float* __restrict__ a, const float* __restrict__ proj, const float* __restrict__ vg,
    float* __restrict__ catB, float* __restrict__ o3g)
{
    __shared__ float ats[8*132];      // 4.2 KB
    __shared__ float vts[40*132];     // 21.1 KB
    int h = blockIdx.x, i0 = blockIdx.y*8;
    int t = threadIdx.x;
    int il = t & 7, rg = (t>>3)&7, jq = t>>6;
    const float* v = proj + 384*N;
    float acc[5] = {};
    for (int jc = 0; jc < 4; jc++) {
        __syncthreads();
        {   // a tile 8x128 float4: 1 per thread
            int ii = t >> 5, j4 = t & 31;
            *(float4*)&ats[ii*132 + j4*4] =
                *(const float4*)&a[((size_t)h*N + i0+ii)*N + jc*128 + j4*4];
        }
        #pragma unroll
        for (int k = 0; k < 5; k++) {  // v/vg tile 40x128 float4
            int idx = t + k*256;
            int r = idx >> 5, j4 = idx & 31;
            const float* src = (r < 16) ? (v + (size_t)(r*H + h)*N)
                : (vg + (size_t)(((r-16)>>3)*96 + h*PV + ((r-16)&7))*N);
            *(float4*)&vts[r*132 + j4*4] = *(const float4*)&src[jc*128 + j4*4];
        }
        __syncthreads();
        #pragma unroll
        for (int s = 0; s < 8; s++) {
            int jo = jq*32 + s*4;
            float4 a4 = *(const float4*)&ats[il*132 + jo];
            #pragma unroll
            for (int r = 0; r < 5; r++) {
                float4 v4 = *(const float4*)&vts[(rg*5+r)*132 + jo];
                acc[r] += v4.x*a4.x + v4.y*a4.y + v4.z*a4.z + v4.w*a4.w;
            }
        }
    }
    __syncthreads();
    if (jq >= 2) {
        float* rb = &ats[((jq-2)*64 + (t & 63))*5];
        #pragma unroll
        for (int r = 0; r < 5; r++) rb[r] = acc[r];
    }
    __syncthreads();
    if (jq < 2) {
        const float* rb = &ats[(jq*64 + (t & 63))*5];
        #pragma unroll
        for (int r = 0; r < 5; r++) acc[r] += rb[r];
        if (jq == 1) {
            float* rb2 = &ats[640 + (t & 63)*5];
            #pragma unroll
            for (int r = 0; r < 5; r++) rb2[r] = acc[r];
        }
    }
    __syncthreads();
    if (jq == 0) {
        const float* rb2 = &ats[640 + t*5];
        #pragma unroll
        for (int r = 0; r < 5; r++) {
            float val = acc[r] + rb2[r];
            int row = rg*5 + r;
            if (row < 16) catB[(size_t)(row*H + h)*N + i0 + il] = val;
            else { int rr = row - 16;
                   o3g[(size_t)((rr>>3)*96 + h*PV + (rr&7))*N + i0 + il] = val; }
        }
    }
}

// ---------------------------------------------------------------------------
// Kernel 6: inverse frame transform -> catB rows [192, 480)
// ---------------------------------------------------------------------------
__global__ void k_o3(const float* __restrict__ o3g,
                     const float* __restrict__ t_r, const float* __restrict__ t_t,
                     float* __restrict__ catB)
{
    int gid = blockIdx.x*blockDim.x + threadIdx.x;
    int i = gid & (N-1), hp = gid >> 9;
    if (hp >= 96) return;
    float x0 = o3g[(size_t)(0*96 + hp)*N + i] - t_t[i*3+0];
    float x1 = o3g[(size_t)(1*96 + hp)*N + i] - t_t[i*3+1];
    float x2 = o3g[(size_t)(2*96 + hp)*N + i] - t_t[i*3+2];
    #pragma unroll
    for (int d = 0; d < 3; d++) {
        float o = t_r[(i*3+0)*3+d]*x0 + t_r[(i*3+1)*3+d]*x1 + t_r[(i*3+2)*3+d]*x2;
        catB[(size_t)(192 + d*96 + hp)*N + i] = o;
    }
}

// ---------------------------------------------------------------------------
// Kernel 6b: o3_norm -> catB row 480.  16 blocks x (32 i x 8 row-groups)
// ---------------------------------------------------------------------------
__global__ void k_norm(float* __restrict__ catB)
{
    __shared__ float red[8][32];
    int il = threadIdx.x & 31, g = threadIdx.x >> 5;
    int i = blockIdx.x*32 + il;
    float acc = 0.f;
    for (int r = g*36; r < g*36 + 36; ++r) {
        float v = catB[(size_t)(192+r)*N + i];
        acc += v*v;
    }
    red[g][il] = acc;
    __syncthreads();
    if (g == 0) {
        acc = 0.f;
        #pragma unroll
        for (int u = 0; u < 8; ++u) acc += red[u][il];
        catB[(size_t)480*N + i] = sqrtf(acc);
    }
}

// ---------------------------------------------------------------------------
// Kernel 7: final GEMM, split-K=4 with atomics.  K chunks [0,512,1024,1536,2017).
// c<1536 reads from o1T[n][c] (transposed in LDS); c>=1536 from catB[c-1536][n].
// ---------------------------------------------------------------------------
__global__ __launch_bounds__(256) void k_final(
    const float* __restrict__ Ws, const float* __restrict__ bs,
    const float* __restrict__ o1T, const float* __restrict__ catB,
    float* __restrict__ out)
{
    __shared__ float Wt[16*33];
    __shared__ float Ct[32*66];
    int o0 = blockIdx.x*16, n0 = blockIdx.y*64;
    int ks = blockIdx.z;
    int kbeg = ks*512, kend = min(CATR, kbeg+512);
    int t = threadIdx.x;
    int og = t >> 6, nl = t & 63;
    float acc[4] = {};
    for (int c0 = kbeg; c0 < kend; c0 += 32) {
        __syncthreads();
        for (int k = 0; k < 2; k++) {
            int idx = t + k*256;
            int oo = idx >> 5, ccol = idx & 31;
            int c = c0 + ccol;
            Wt[oo*33 + ccol] = (c < kend) ? Ws[(size_t)(o0+oo)*CATR + c] : 0.f;
        }
        if (ks < 3) {
            for (int k = 0; k < 2; k++) {
                int idx = t + k*256;
                int nn = idx >> 3, c4 = idx & 7;
                float4 v = *(const float4*)&o1T[(size_t)(n0+nn)*1536 + c0 + c4*4];
                Ct[(c4*4+0)*66 + nn] = v.x;
                Ct[(c4*4+1)*66 + nn] = v.y;
                Ct[(c4*4+2)*66 + nn] = v.z;
                Ct[(c4*4+3)*66 + nn] = v.w;
            }
        } else {
            for (int k = 0; k < 4; k++) {
                int idx = t + k*256;
                int ccr = idx >> 5, j2 = idx & 31;
                int c = c0 + ccr;
                float2 vv; vv.x = 0.f; vv.y = 0.f;
                if (c < kend) vv = *(const float2*)&catB[(size_t)(c-1536)*N + n0 + j2*2];
                *(float2*)&Ct[ccr*66 + j2*2] = vv;
            }
        }
        __syncthreads();
        int klim = min(32, kend - c0);
        for (int kk = 0; kk < klim; kk++) {
            float cv = Ct[kk*66 + nl];
            #pragma unroll
            for (int r = 0; r < 4; r++)
                acc[r] += Wt[(og*4+r)*33 + kk] * cv;
        }
    }
    #pragma unroll
    for (int r = 0; r < 4; r++) {
        int o = o0 + og*4 + r;
        float val = acc[r];
        if (ks == 0) val += bs[o];
        atomicAdd(&out[(size_t)o*N + n0 + nl], val);
    }
}

// ---------------------------------------------------------------------------
extern "C" void kernel_launch(void* const* d_in, const int* in_sizes, int n_in,
                              void* d_out, int out_size, void* d_ws, size_t ws_size,
                              hipStream_t stream)
{
    const float* s     = (const float*)d_in[0];
    const float* z     = (const float*)d_in[1];
    const float* t_r   = (const float*)d_in[2];
    const float* t_t   = (const float*)d_in[3];
    const float* Wq    = (const float*)d_in[4];
    const float* Wk    = (const float*)d_in[5];
    const float* Wv    = (const float*)d_in[6];
    const float* Wqp   = (const float*)d_in[7];
    const float* Wkp   = (const float*)d_in[8];
    const float* Wvp   = (const float*)d_in[9];
    const float* Wb    = (const float*)d_in[10];
    const float* gamma = (const float*)d_in[11];
    const float* Ws    = (const float*)d_in[12];
    const float* bs    = (const float*)d_in[13];
    float* out = (float*)d_out;

    float* ws   = (float*)d_ws;
    float* proj = ws;                       // 1152*512
    float* qg   = proj + 1152*N;            // 144*512
    float* kg   = qg   + 144*N;             // 144*512
    float* vg   = kg   + 144*N;             // 288*512
    float* o3g  = vg   + 288*N;             // 288*512
    float* a    = o3g  + 288*N;             // 12*512*512 (partial logits, then a)
    float* o1T  = a    + (size_t)H*N*N;     // 512*1536 (o1 transposed: [i][c*12+h])
    float* catB = o1T  + (size_t)N*1536;    // 481*512  (o2/o3/norm rows)

    k_proj   <<<dim3(72,4),    256, 0, stream>>>(s, Wq, Wk, Wv, Wqp, Wkp, Wvp, proj);
    k_frames <<<384,           256, 0, stream>>>(proj, t_r, t_t, qg, kg, vg);
    k_qkgeom <<<dim3(12,16,4), 256, 0, stream>>>(proj, qg, kg, gamma, a);
    k_zbias  <<<dim3(512,8),   256, 0, stream>>>(z, Wb, a);
    k_softmax<<<512,           512, 0, stream>>>(a);
    k_o1     <<<dim3(512,2),   256, 0, stream>>>(a, z, o1T);
    k_o2o3g  <<<dim3(12,64),   256, 0, stream>>>(a, proj, vg, catB, o3g);
    k_o3     <<<192,           256, 0, stream>>>(o3g, t_r, t_t, catB);
    k_norm   <<<16,            256, 0, stream>>>(catB);
    hipMemsetAsync(out, 0, (size_t)CS*N*sizeof(float), stream);
    k_final  <<<dim3(24,8,4),  256, 0, stream>>>(Ws, bs, o1T, catB, out);
}

// Round 8
// 370.149 us; speedup vs baseline: 1.1081x; 1.1081x over previous
//
#include <hip/hip_runtime.h>
#include <math.h>

#define N 512
#define H 12
#define CC 16      // C
#define CZ 128
#define CS 384
#define PQ 4
#define PV 8
#define CATR 2017

// ---------------------------------------------------------------------------
// Kernel 1: all projections. out[o,n] = sum_c W_sel[o][c] * s[c,n], o in [0,1152)
// q rows (o<192) PRE-SCALED by 0.25 (consumed only by the qk/4 term).
// ---------------------------------------------------------------------------
__global__ __launch_bounds__(256) void k_proj(
    const float* __restrict__ s,
    const float* __restrict__ Wq, const float* __restrict__ Wk, const float* __restrict__ Wv,
    const float* __restrict__ Wqp, const float* __restrict__ Wkp, const float* __restrict__ Wvp,
    float* __restrict__ proj)
{
    __shared__ float Wt[16][33];
    __shared__ float St[32][128];
    int t = threadIdx.x;
    int o0 = blockIdx.x * 16;
    int n0 = blockIdx.y * 128;
    const float* Wsrc; int orow;
    if (o0 < 192)      { Wsrc = Wq;  orow = o0; }
    else if (o0 < 384) { Wsrc = Wk;  orow = o0-192; }
    else if (o0 < 576) { Wsrc = Wv;  orow = o0-384; }
    else if (o0 < 720) { Wsrc = Wqp; orow = o0-576; }
    else if (o0 < 864) { Wsrc = Wkp; orow = o0-720; }
    else               { Wsrc = Wvp; orow = o0-864; }

    int og = t >> 6, nl = t & 63;
    float acc[4][2] = {};
    for (int c0 = 0; c0 < CS; c0 += 32) {
        __syncthreads();
        for (int k = 0; k < 2; k++) {
            int idx = t + k*256;
            int oo = idx >> 5, ccol = idx & 31;
            Wt[oo][ccol] = Wsrc[(orow+oo)*CS + c0 + ccol];
        }
        for (int k = 0; k < 4; k++) {
            int idx = t + k*256;
            int ccr = idx >> 5, nn4 = idx & 31;
            float4 v = *(const float4*)&s[(c0+ccr)*N + n0 + nn4*4];
            *(float4*)&St[ccr][nn4*4] = v;
        }
        __syncthreads();
        for (int kk = 0; kk < 32; kk++) {
            float sv0 = St[kk][nl], sv1 = St[kk][nl+64];
            #pragma unroll
            for (int r = 0; r < 4; r++) {
                float w = Wt[og*4+r][kk];
                acc[r][0] += w * sv0;
                acc[r][1] += w * sv1;
            }
        }
    }
    float scale = (o0 < 192) ? 0.25f : 1.0f;
    for (int r = 0; r < 4; r++) {
        int o = o0 + og*4 + r;
        proj[o*N + n0 + nl]      = scale * acc[r][0];
        proj[o*N + n0 + 64 + nl] = scale * acc[r][1];
    }
}

// ---------------------------------------------------------------------------
// Kernel 2: apply frames.
// ---------------------------------------------------------------------------
__global__ void k_frames(const float* __restrict__ proj,
                         const float* __restrict__ t_r, const float* __restrict__ t_t,
                         float* __restrict__ qg, float* __restrict__ kg, float* __restrict__ vg)
{
    int gid = blockIdx.x * blockDim.x + threadIdx.x;
    int n = gid & (N-1);
    int hp = gid >> 9;
    if (hp >= 192) return;
    const float* src; float* dst; int rowb, stride;
    if (hp < 48)      { src = proj + 576*N; dst = qg; rowb = hp;    stride = 48; }
    else if (hp < 96) { src = proj + 720*N; dst = kg; rowb = hp-48; stride = 48; }
    else              { src = proj + 864*N; dst = vg; rowb = hp-96; stride = 96; }
    float x0 = src[(rowb + 0*stride)*N + n];
    float x1 = src[(rowb + 1*stride)*N + n];
    float x2 = src[(rowb + 2*stride)*N + n];
    #pragma unroll
    for (int d = 0; d < 3; d++) {
        float r0 = t_r[(n*3+d)*3+0], r1 = t_r[(n*3+d)*3+1], r2 = t_r[(n*3+d)*3+2];
        dst[(rowb + d*stride)*N + n] = r0*x0 + r1*x1 + r2*x2 + t_t[n*3+d];
    }
}

// ---------------------------------------------------------------------------
// Kernel 3a: qk + geometric logit partial as a tiled outer-product GEMM.
// Writes raw partial into `a`.  (R6-proven.)
// ---------------------------------------------------------------------------
__global__ __launch_bounds__(256) void k_qkgeom(
    const float* __restrict__ proj, const float* __restrict__ qg,
    const float* __restrict__ kg, const float* __restrict__ gamma,
    float* __restrict__ a)
{
    __shared__ float Qe[30][32];
    __shared__ float Ke[30][128];
    const int h  = blockIdx.x;
    const int i0 = blockIdx.y * 32;
    const int j0 = blockIdx.z * 128;
    const int t  = threadIdx.x;
    const float w_c2 = 0.11785113019775793f;   // sqrt(1/18)/2
    float g = gamma[h];
    float sp = (g > 20.f) ? g : log1pf(expf(g));
    float ch = sp * w_c2;

    for (int idx = t; idx < 28*32; idx += 256) {
        int row = idx >> 5, col = idx & 31;
        float v;
        if (row < 16) v = proj[(size_t)(row*12 + h)*N + i0 + col];
        else { int dp = row-16, d = dp>>2, p = dp&3;
               v = 2.f*ch * qg[(size_t)(d*48 + h*4 + p)*N + i0 + col]; }
        Qe[row][col] = v;
    }
    for (int idx = t; idx < 28*128; idx += 256) {
        int row = idx >> 7, col = idx & 127;
        float v;
        if (row < 16) v = proj[(size_t)((192 + row*12 + h))*N + j0 + col];
        else { int dp = row-16, d = dp>>2, p = dp&3;
               v = kg[(size_t)(d*48 + h*4 + p)*N + j0 + col]; }
        Ke[row][col] = v;
    }
    if (t < 32) {
        float q2 = 0.f;
        #pragma unroll
        for (int dp = 0; dp < 12; ++dp) {
            int d = dp>>2, p = dp&3;
            float v = qg[(size_t)(d*48 + h*4 + p)*N + i0 + t];
            q2 = fmaf(v, v, q2);
        }
        Qe[28][t] = 1.f;
        Qe[29][t] = -ch * q2;
    } else if (t < 160) {
        int col = t - 32;
        float k2 = 0.f;
        #pragma unroll
        for (int dp = 0; dp < 12; ++dp) {
            int d = dp>>2, p = dp&3;
            float v = kg[(size_t)(d*48 + h*4 + p)*N + j0 + col];
            k2 = fmaf(v, v, k2);
        }
        Ke[28][col] = -ch * k2;
        Ke[29][col] = 1.f;
    }
    __syncthreads();

    const int tj = t & 31, ti = t >> 5;     // thread: 4 i rows x 4 j cols
    float acc[4][4] = {};
    #pragma unroll
    for (int c = 0; c < 30; ++c) {
        float4 k4 = *(const float4*)&Ke[c][tj*4];
        float4 q4 = *(const float4*)&Qe[c][ti*4];
        float qr[4] = {q4.x, q4.y, q4.z, q4.w};
        #pragma unroll
        for (int r = 0; r < 4; ++r) {
            acc[r][0] = fmaf(qr[r], k4.x, acc[r][0]);
            acc[r][1] = fmaf(qr[r], k4.y, acc[r][1]);
            acc[r][2] = fmaf(qr[r], k4.z, acc[r][2]);
            acc[r][3] = fmaf(qr[r], k4.w, acc[r][3]);
        }
    }
    #pragma unroll
    for (int r = 0; r < 4; ++r) {
        float4 v; v.x = acc[r][0]; v.y = acc[r][1]; v.z = acc[r][2]; v.w = acc[r][3];
        *(float4*)&a[((size_t)h*N + i0 + ti*4 + r)*N + j0 + tj*4] = v;
    }
}

// ---------------------------------------------------------------------------
// Kernel 3b: z-bias accumulation, RMW into `a`.  Round-8: float4 z loads
// (R7's scalar 4B loads = 4 KB/wave in flight -> 0.9 TB/s, VALUBusy 16%;
// G13: scalar fp32 streams cost ~2-2.5x).  Grid (512 i, 2 j-halves of 256);
// 256 thr = 64 j-quads x 4 c-groups of 32.  8 float4 in flight per thread
// (8 KB/wave).  One LDS slab reduce, float4 RMW into `a`.
// NO min-waves in launch_bounds (R4 lesson: min-waves floor + high live
// state = catastrophic spill).
// ---------------------------------------------------------------------------
__global__ __launch_bounds__(256) void k_zbias(
    const float* __restrict__ z, const float* __restrict__ Wb,
    float* __restrict__ a)
{
    __shared__ float red[3][64][49];      // 3 slabs x 64 jq x 48 (+1 pad) = 37.6 KB
    const int i  = blockIdx.x;
    const int j0 = blockIdx.y * 256;
    const int t  = threadIdx.x;
    const int jq = t & 63;                               // j-quad: j = j0 + jq*4
    const int cg = __builtin_amdgcn_readfirstlane(t >> 6);  // c-group, wave-uniform
    const size_t NN = (size_t)N * N;

    const float* zp = z + (size_t)(cg*32)*NN + (size_t)i*N + j0 + jq*4;
    float acc[12][4] = {};
    for (int cb = 0; cb < 32; cb += 8) {
        float4 zb[8];
        #pragma unroll
        for (int u = 0; u < 8; ++u)
            zb[u] = *(const float4*)(zp + (size_t)(cb+u)*NN);
        #pragma unroll
        for (int h = 0; h < 12; ++h) {
            #pragma unroll
            for (int u = 0; u < 8; ++u) {
                float w = Wb[h*CZ + cg*32 + cb + u];      // uniform -> s_load
                acc[h][0] = fmaf(w, zb[u].x, acc[h][0]);
                acc[h][1] = fmaf(w, zb[u].y, acc[h][1]);
                acc[h][2] = fmaf(w, zb[u].z, acc[h][2]);
                acc[h][3] = fmaf(w, zb[u].w, acc[h][3]);
            }
        }
    }
    if (cg > 0) {
        float* rb = red[cg-1][jq];
        #pragma unroll
        for (int h = 0; h < 12; ++h)
            #pragma unroll
            for (int r = 0; r < 4; ++r) rb[h*4+r] = acc[h][r];
    }
    __syncthreads();
    if (cg == 0) {
        #pragma unroll
        for (int sl = 0; sl < 3; ++sl) {
            const float* rb = red[sl][jq];
            #pragma unroll
            for (int h = 0; h < 12; ++h)
                #pragma unroll
                for (int r = 0; r < 4; ++r) acc[h][r] += rb[h*4+r];
        }
        #pragma unroll
        for (int h = 0; h < 12; ++h) {
            float4* ap = (float4*)&a[((size_t)h*N + i)*N + j0 + jq*4];
            float4 av = *ap;
            av.x += acc[h][0]; av.y += acc[h][1];
            av.z += acc[h][2]; av.w += acc[h][3];
            *ap = av;                      // single writer per element
        }
    }
}

// ---------------------------------------------------------------------------
// Kernel 3c: softmax over j, in place on `a` (scales by w_l).  Block per i,
// 512 threads (lane t = j); two-level reduce (shfl intra-wave, LDS cross-wave).
// ---------------------------------------------------------------------------
__global__ __launch_bounds__(512) void k_softmax(float* __restrict__ a)
{
    __shared__ float pm[12][8];
    __shared__ float ps[12][8];
    const int i = blockIdx.x;
    const int t = threadIdx.x;
    const int w = t >> 6;
    const int l = t & 63;
    const float w_l = 0.57735026918962584f;   // sqrt(1/3)

    float lv[12], mw[12];
    #pragma unroll
    for (int h = 0; h < 12; ++h)
        lv[h] = w_l * a[((size_t)h*N + i)*N + t];

    #pragma unroll
    for (int h = 0; h < 12; ++h) {
        float m = lv[h];
        for (int s = 32; s; s >>= 1) m = fmaxf(m, __shfl_xor(m, s));
        float e = __expf(lv[h] - m);
        float sm = e;
        for (int s = 32; s; s >>= 1) sm += __shfl_xor(sm, s);
        lv[h] = e; mw[h] = m;
        if (l == 0) { pm[h][w] = m; ps[h][w] = sm; }
    }
    __syncthreads();
    #pragma unroll
    for (int h = 0; h < 12; ++h) {
        float mg = pm[h][0];
        #pragma unroll
        for (int u = 1; u < 8; ++u) mg = fmaxf(mg, pm[h][u]);
        float sg = 0.f;
        #pragma unroll
        for (int u = 0; u < 8; ++u) sg += ps[h][u] * __expf(pm[h][u] - mg);
        float f = __expf(mw[h] - mg) / sg;       // uniform per (wave,h)
        a[((size_t)h*N + i)*N + t] = lv[h] * f;
    }
}

// ---------------------------------------------------------------------------
// Kernel 4: o1 = sum_j a[h,i,j]*z[c,i,j].  Grid (512 i, 2 c-halves), all j
// in-block.  Output to o1T[i][c*12+h] (transposed -> coalesced writes).
// ---------------------------------------------------------------------------
__global__ __launch_bounds__(256, 8) void k_o1(
    const float* __restrict__ a, const float* __restrict__ z,
    float* __restrict__ o1T)
{
    __shared__ float zls[64*36];     // 9.2 KB: z half-tile 64c x 32j; reduce slabs after
    __shared__ float als[12][36];    // 1.7 KB: a tile 12 x 32j
    const int i  = blockIdx.x;
    const int c0 = blockIdx.y * 64;
    const int t  = threadIdx.x;
    const int cg = t & 31, hg = (t >> 5) & 1, jq = t >> 6;

    float acc[2][6] = {};
    for (int jc = 0; jc < 16; ++jc) {
        __syncthreads();
        #pragma unroll
        for (int k = 0; k < 2; ++k) {        // stage z: 64c x 32j
            int idx = t + k*256;
            int c = idx >> 3, j4 = idx & 7;
            *(float4*)&zls[c*36 + j4*4] =
                *(const float4*)&z[((size_t)(c0+c)*N + i)*N + jc*32 + j4*4];
        }
        if (t < 96) {                        // stage a: 12h x 32j
            int h = t >> 3, j4 = t & 7;
            *(float4*)&als[h][j4*4] =
                *(const float4*)&a[((size_t)h*N + i)*N + jc*32 + j4*4];
        }
        __syncthreads();
        #pragma unroll
        for (int s = 0; s < 2; ++s) {
            int jo = jq*8 + s*4;
            float4 a4[6];
            #pragma unroll
            for (int hh = 0; hh < 6; ++hh)
                a4[hh] = *(const float4*)&als[hg*6+hh][jo];   // broadcast
            #pragma unroll
            for (int r = 0; r < 2; ++r) {
                float4 z4 = *(const float4*)&zls[(cg + 32*r)*36 + jo];
                #pragma unroll
                for (int hh = 0; hh < 6; ++hh)
                    acc[r][hh] += z4.x*a4[hh].x + z4.y*a4[hh].y
                                + z4.z*a4[hh].z + z4.w*a4[hh].w;
            }
        }
    }
    // cross-wave (jq) reduce via slabs in zls; stride 13 = conflict-light
    const int sl = t & 63;
    __syncthreads();
    if (jq >= 2) {
        float* rb = &zls[(jq-2)*832 + sl*13];
        #pragma unroll
        for (int r = 0; r < 2; ++r)
            #pragma unroll
            for (int hh = 0; hh < 6; ++hh) rb[r*6+hh] = acc[r][hh];
    }
    __syncthreads();
    if (jq < 2) {
        const float* rb = &zls[jq*832 + sl*13];
        #pragma unroll
        for (int r = 0; r < 2; ++r)
            #pragma unroll
            for (int hh = 0; hh < 6; ++hh) acc[r][hh] += rb[r*6+hh];
    }
    __syncthreads();                          // slab0 reads done before jq1 overwrites
    if (jq == 1) {
        float* rb = &zls[sl*13];
        #pragma unroll
        for (int r = 0; r < 2; ++r)
            #pragma unroll
            for (int hh = 0; hh < 6; ++hh) rb[r*6+hh] = acc[r][hh];
    }
    __syncthreads();
    if (jq == 0) {
        const float* rb = &zls[sl*13];
        #pragma unroll
        for (int r = 0; r < 2; ++r)
            #pragma unroll
            for (int hh = 0; hh < 3; ++hh) {
                int c = c0 + cg + 32*r, h = hg*6 + hh*2;
                float2 v2;
                v2.x = acc[r][hh*2]   + rb[r*6+hh*2];
                v2.y = acc[r][hh*2+1] + rb[r*6+hh*2+1];
                *(float2*)&o1T[(size_t)i*1536 + c*12 + h] = v2;
            }
    }
}

// ---------------------------------------------------------------------------
// Kernel 5: o2 + o3g. grid (12 h, 64 i-tiles of 8). 4-way j split.
// o2 -> catB rows [0,192); o3g unchanged.
// ---------------------------------------------------------------------------
__global__ __launch_bounds__(256) void k_o2o3g(
    const float* __restrict__ a, const float* __restrict__ proj, const float* __restrict__ vg,
    float* __restrict__ catB, float* __restrict__ o3g)
{
    __shared__ float ats[8*132];      // 4.2 KB
    __shared__ float vts[40*132];     // 21.1 KB
    int h = blockIdx.x, i0 = blockIdx.y*8;
    int t = threadIdx.x;
    int il = t & 7, rg = (t>>3)&7, jq = t>>6;
    const float* v = proj + 384*N;
    float acc[5] = {};
    for (int jc = 0; jc < 4; jc++) {
        __syncthreads();
        {   // a tile 8x128 float4: 1 per thread
            int ii = t >> 5, j4 = t & 31;
            *(float4*)&ats[ii*132 + j4*4] =
                *(const float4*)&a[((size_t)h*N + i0+ii)*N + jc*128 + j4*4];
        }
        #pragma unroll
        for (int k = 0; k < 5; k++) {  // v/vg tile 40x128 float4
            int idx = t + k*256;
            int r = idx >> 5, j4 = idx & 31;
            const float* src = (r < 16) ? (v + (size_t)(r*H + h)*N)
                : (vg + (size_t)(((r-16)>>3)*96 + h*PV + ((r-16)&7))*N);
            *(float4*)&vts[r*132 + j4*4] = *(const float4*)&src[jc*128 + j4*4];
        }
        __syncthreads();
        #pragma unroll
        for (int s = 0; s < 8; s++) {
            int jo = jq*32 + s*4;
            float4 a4 = *(const float4*)&ats[il*132 + jo];
            #pragma unroll
            for (int r = 0; r < 5; r++) {
                float4 v4 = *(const float4*)&vts[(rg*5+r)*132 + jo];
                acc[r] += v4.x*a4.x + v4.y*a4.y + v4.z*a4.z + v4.w*a4.w;
            }
        }
    }
    __syncthreads();
    if (jq >= 2) {
        float* rb = &ats[((jq-2)*64 + (t & 63))*5];
        #pragma unroll
        for (int r = 0; r < 5; r++) rb[r] = acc[r];
    }
    __syncthreads();
    if (jq < 2) {
        const float* rb = &ats[(jq*64 + (t & 63))*5];
        #pragma unroll
        for (int r = 0; r < 5; r++) acc[r] += rb[r];
        if (jq == 1) {
            float* rb2 = &ats[640 + (t & 63)*5];
            #pragma unroll
            for (int r = 0; r < 5; r++) rb2[r] = acc[r];
        }
    }
    __syncthreads();
    if (jq == 0) {
        const float* rb2 = &ats[640 + t*5];
        #pragma unroll
        for (int r = 0; r < 5; r++) {
            float val = acc[r] + rb2[r];
            int row = rg*5 + r;
            if (row < 16) catB[(size_t)(row*H + h)*N + i0 + il] = val;
            else { int rr = row - 16;
                   o3g[(size_t)((rr>>3)*96 + h*PV + (rr&7))*N + i0 + il] = val; }
        }
    }
}

// ---------------------------------------------------------------------------
// Kernel 6: inverse frame transform -> catB rows [192, 480)
// ---------------------------------------------------------------------------
__global__ void k_o3(const float* __restrict__ o3g,
                     const float* __restrict__ t_r, const float* __restrict__ t_t,
                     float* __restrict__ catB)
{
    int gid = blockIdx.x*blockDim.x + threadIdx.x;
    int i = gid & (N-1), hp = gid >> 9;
    if (hp >= 96) return;
    float x0 = o3g[(size_t)(0*96 + hp)*N + i] - t_t[i*3+0];
    float x1 = o3g[(size_t)(1*96 + hp)*N + i] - t_t[i*3+1];
    float x2 = o3g[(size_t)(2*96 + hp)*N + i] - t_t[i*3+2];
    #pragma unroll
    for (int d = 0; d < 3; d++) {
        float o = t_r[(i*3+0)*3+d]*x0 + t_r[(i*3+1)*3+d]*x1 + t_r[(i*3+2)*3+d]*x2;
        catB[(size_t)(192 + d*96 + hp)*N + i] = o;
    }
}

// ---------------------------------------------------------------------------
// Kernel 6b: o3_norm -> catB row 480.  16 blocks x (32 i x 8 row-groups)
// ---------------------------------------------------------------------------
__global__ void k_norm(float* __restrict__ catB)
{
    __shared__ float red[8][32];
    int il = threadIdx.x & 31, g = threadIdx.x >> 5;
    int i = blockIdx.x*32 + il;
    float acc = 0.f;
    for (int r = g*36; r < g*36 + 36; ++r) {
        float v = catB[(size_t)(192+r)*N + i];
        acc += v*v;
    }
    red[g][il] = acc;
    __syncthreads();
    if (g == 0) {
        acc = 0.f;
        #pragma unroll
        for (int u = 0; u < 8; ++u) acc += red[u][il];
        catB[(size_t)480*N + i] = sqrtf(acc);
    }
}

// ---------------------------------------------------------------------------
// Kernel 7: final GEMM, split-K=4 with atomics.  K chunks [0,512,1024,1536,2017).
// c<1536 reads from o1T[n][c] (transposed in LDS); c>=1536 from catB[c-1536][n].
// ---------------------------------------------------------------------------
__global__ __launch_bounds__(256) void k_final(
    const float* __restrict__ Ws, const float* __restrict__ bs,
    const float* __restrict__ o1T, const float* __restrict__ catB,
    float* __restrict__ out)
{
    __shared__ float Wt[16*33];
    __shared__ float Ct[32*66];
    int o0 = blockIdx.x*16, n0 = blockIdx.y*64;
    int ks = blockIdx.z;
    int kbeg = ks*512, kend = min(CATR, kbeg+512);
    int t = threadIdx.x;
    int og = t >> 6, nl = t & 63;
    float acc[4] = {};
    for (int c0 = kbeg; c0 < kend; c0 += 32) {
        __syncthreads();
        for (int k = 0; k < 2; k++) {
            int idx = t + k*256;
            int oo = idx >> 5, ccol = idx & 31;
            int c = c0 + ccol;
            Wt[oo*33 + ccol] = (c < kend) ? Ws[(size_t)(o0+oo)*CATR + c] : 0.f;
        }
        if (ks < 3) {
            for (int k = 0; k < 2; k++) {
                int idx = t + k*256;
                int nn = idx >> 3, c4 = idx & 7;
                float4 v = *(const float4*)&o1T[(size_t)(n0+nn)*1536 + c0 + c4*4];
                Ct[(c4*4+0)*66 + nn] = v.x;
                Ct[(c4*4+1)*66 + nn] = v.y;
                Ct[(c4*4+2)*66 + nn] = v.z;
                Ct[(c4*4+3)*66 + nn] = v.w;
            }
        } else {
            for (int k = 0; k < 4; k++) {
                int idx = t + k*256;
                int ccr = idx >> 5, j2 = idx & 31;
                int c = c0 + ccr;
                float2 vv; vv.x = 0.f; vv.y = 0.f;
                if (c < kend) vv = *(const float2*)&catB[(size_t)(c-1536)*N + n0 + j2*2];
                *(float2*)&Ct[ccr*66 + j2*2] = vv;
            }
        }
        __syncthreads();
        int klim = min(32, kend - c0);
        for (int kk = 0; kk < klim; kk++) {
            float cv = Ct[kk*66 + nl];
            #pragma unroll
            for (int r = 0; r < 4; r++)
                acc[r] += Wt[(og*4+r)*33 + kk] * cv;
        }
    }
    #pragma unroll
    for (int r = 0; r < 4; r++) {
        int o = o0 + og*4 + r;
        float val = acc[r];
        if (ks == 0) val += bs[o];
        atomicAdd(&out[(size_t)o*N + n0 + nl], val);
    }
}

// ---------------------------------------------------------------------------
extern "C" void kernel_launch(void* const* d_in, const int* in_sizes, int n_in,
                              void* d_out, int out_size, void* d_ws, size_t ws_size,
                              hipStream_t stream)
{
    const float* s     = (const float*)d_in[0];
    const float* z     = (const float*)d_in[1];
    const float* t_r   = (const float*)d_in[2];
    const float* t_t   = (const float*)d_in[3];
    const float* Wq    = (const float*)d_in[4];
    const float* Wk    = (const float*)d_in[5];
    const float* Wv    = (const float*)d_in[6];
    const float* Wqp   = (const float*)d_in[7];
    const float* Wkp   = (const float*)d_in[8];
    const float* Wvp   = (const float*)d_in[9];
    const float* Wb    = (const float*)d_in[10];
    const float* gamma = (const float*)d_in[11];
    const float* Ws    = (const float*)d_in[12];
    const float* bs    = (const float*)d_in[13];
    float* out = (float*)d_out;

    float* ws   = (float*)d_ws;
    float* proj = ws;                       // 1152*512
    float* qg   = proj + 1152*N;            // 144*512
    float* kg   = qg   + 144*N;             // 144*512
    float* vg   = kg   + 144*N;             // 288*512
    float* o3g  = vg   + 288*N;             // 288*512
    float* a    = o3g  + 288*N;             // 12*512*512 (partial logits, then a)
    float* o1T  = a    + (size_t)H*N*N;     // 512*1536 (o1 transposed: [i][c*12+h])
    float* catB = o1T  + (size_t)N*1536;    // 481*512  (o2/o3/norm rows)

    k_proj   <<<dim3(72,4),    256, 0, stream>>>(s, Wq, Wk, Wv, Wqp, Wkp, Wvp, proj);
    k_frames <<<384,           256, 0, stream>>>(proj, t_r, t_t, qg, kg, vg);
    k_qkgeom <<<dim3(12,16,4), 256, 0, stream>>>(proj, qg, kg, gamma, a);
    k_zbias  <<<dim3(512,2),   256, 0, stream>>>(z, Wb, a);
    k_softmax<<<512,           512, 0, stream>>>(a);
    k_o1     <<<dim3(512,2),   256, 0, stream>>>(a, z, o1T);
    k_o2o3g  <<<dim3(12,64),   256, 0, stream>>>(a, proj, vg, catB, o3g);
    k_o3     <<<192,           256, 0, stream>>>(o3g, t_r, t_t, catB);
    k_norm   <<<16,            256, 0, stream>>>(catB);
    hipMemsetAsync(out, 0, (size_t)CS*N*sizeof(float), stream);
    k_final  <<<dim3(24,8,4),  256, 0, stream>>>(Ws, bs, o1T, catB, out);
}